// Round 13
// baseline (303.320 us; speedup 1.0000x reference)
//
#include <hip/hip_runtime.h>

#define NEG_INF -1e30f

typedef __attribute__((ext_vector_type(8))) __bf16 bf16x8;
typedef __attribute__((ext_vector_type(4))) float f32x4;

constexpr int Bb = 16, T = 800, D = 512, V = 5000, L = 100;
constexpr int ROWS = Bb * T;        // 12800
constexpr int S = 2 * L + 1;        // 201
constexpr int SP = 208;             // padded S (13*16)
constexpr int VP = 5120;            // V padded to 128
constexpr int NCB = VP / 128;       // 40 col-blocks (GEMM)
constexpr int NRB = ROWS / 128;     // 100 row-blocks
constexpr int NGB = Bb * 50;        // 800 gather blocks
constexpr int CONVB = ROWS * D / 1024;  // 6400 conv blocks
constexpr int RSTRIDE = SP * 4;     // 832 bytes per glog row
constexpr int CH = 16;              // DP chunk (t-steps per LDS buffer)
constexpr int CHB = CH * RSTRIDE;   // 13312 bytes per chunk buffer

// float -> bf16 bits, round-to-nearest-even
static __device__ __forceinline__ unsigned short f2bf(float x) {
  union { float f; unsigned u; } v; v.f = x;
  unsigned r = (v.u + 0x7FFFu + ((v.u >> 16) & 1u)) >> 16;
  return (unsigned short)r;
}

// wave_shr:1 (0x138): lane i gets lane i-1; old=0 for lane 0
static __device__ __forceinline__ double dpp_shr1_zero_d(double x) {
  long long b = __double_as_longlong(x);
  int lo = (int)(b & 0xFFFFFFFFLL);
  int hi = (int)(b >> 32);
  int nlo = __builtin_amdgcn_update_dpp(0, lo, 0x138, 0xF, 0xF, false);
  int nhi = __builtin_amdgcn_update_dpp(0, hi, 0x138, 0xF, 0xF, false);
  return __longlong_as_double(((long long)(unsigned)nlo) | ((long long)nhi << 32));
}
// wave_shl:1 (0x130): lane i gets lane i+1; old=0 for lane 63
static __device__ __forceinline__ double dpp_shl1_zero_d(double x) {
  long long b = __double_as_longlong(x);
  int lo = (int)(b & 0xFFFFFFFFLL);
  int hi = (int)(b >> 32);
  int nlo = __builtin_amdgcn_update_dpp(0, lo, 0x130, 0xF, 0xF, false);
  int nhi = __builtin_amdgcn_update_dpp(0, hi, 0x130, 0xF, 0xF, false);
  return __longlong_as_double(((long long)(unsigned)nlo) | ((long long)nhi << 32));
}
static __device__ __forceinline__ float dpp_shl1_zero_f(float x) {
  return __int_as_float(__builtin_amdgcn_update_dpp(
      0, __float_as_int(x), 0x130, 0xF, 0xF, false));
}

// native base-2 transcendentals
static __device__ __forceinline__ float ex2(float x) { return __builtin_amdgcn_exp2f(x); }
static __device__ __forceinline__ float lg2(float x) { return __builtin_amdgcn_logf(x); }

// log2 of a positive double via exponent field + f32 mantissa log
static __device__ __forceinline__ float lg2d(double z) {
  long long b = __double_as_longlong(z);
  int e = (int)((b >> 52) & 0x7FF);
  if (e == 0) return -1.0e30f;            // zero/subnormal -> semiring zero
  unsigned mant = (unsigned)((b >> 29) & 0x7FFFFFu);
  float mf = __int_as_float(0x3F800000u | mant);
  return (float)(e - 1023) + lg2(mf);
}

// ---- PREP: conv_hs (blocks 0..6399) + transW (6400..7039) ----
__global__ __launch_bounds__(256) void k_prep(const float* __restrict__ hs,
                                              const float* __restrict__ W,
                                              unsigned short* __restrict__ A,
                                              unsigned short* __restrict__ Wt) {
  __shared__ float tile[64][65];
  int blk = blockIdx.x;
  if (blk < CONVB) {
    int i = blk * 256 + threadIdx.x;
    float4 f = ((const float4*)hs)[i];
    ushort4 o;
    o.x = f2bf(f.x); o.y = f2bf(f.y); o.z = f2bf(f.z); o.w = f2bf(f.w);
    ((ushort4*)A)[i] = o;
    return;
  }
  int g = blk - CONVB;                 // 0..639
  int v0 = (g % (VP / 64)) * 64, k0 = (g / (VP / 64)) * 64;
  int tl = threadIdx.x & 63, th = threadIdx.x >> 6;
#pragma unroll
  for (int i = 0; i < 16; i++) {
    int k = k0 + th + i * 4;
    int v = v0 + tl;
    tile[th + i * 4][tl] = (v < V) ? W[(size_t)k * V + v] : 0.f;
  }
  __syncthreads();
#pragma unroll
  for (int i = 0; i < 16; i++) {
    int v = v0 + th + i * 4;
    int k = k0 + tl;
    Wt[(size_t)v * D + k] = f2bf(tile[tl][th + i * 4]);
  }
}

// ---- gathered RAW logits: one block per (b, 16-t chunk) ----
__global__ __launch_bounds__(256) void k_gather(const unsigned short* __restrict__ A,
                                                const unsigned short* __restrict__ Wt,
                                                const float* __restrict__ bias,
                                                const int* __restrict__ labels,
                                                float* __restrict__ glog) {
  int tid = threadIdx.x;
  int lane = tid & 63, w = tid >> 6;
  int q = lane >> 4, c = lane & 15;
  int b = blockIdx.x & 15, chk = blockIdx.x >> 4;
  int t0 = chk * 16;
  int bT = b * T, bL = b * L;
  int st0 = (w == 0) ? 0 : 4 + (w - 1) * 3;   // tiles: 4,3,3,3
  int nst = (w == 0) ? 4 : 3;

  int evs[4]; float bvs[4];
#pragma unroll
  for (int j = 0; j < 4; j++) {
    int st = st0 + (j < nst ? j : nst - 1);
    int s = st * 16 + c;
    evs[j] = (s < S && (s & 1)) ? labels[bL + (s >> 1)] : 0;
    bvs[j] = bias[evs[j]];
  }
  const unsigned short* Arow = A + (size_t)(bT + t0 + c) * D;
  f32x4 acc[4];
#pragma unroll
  for (int j = 0; j < 4; j++) acc[j] = (f32x4){0.f, 0.f, 0.f, 0.f};
  for (int kk = 0; kk < D; kk += 32) {
    bf16x8 aa = *(const bf16x8*)(Arow + kk + q * 8);
#pragma unroll
    for (int j = 0; j < 4; j++) {
      bf16x8 bb = *(const bf16x8*)(Wt + (size_t)evs[j] * D + kk + q * 8);
      acc[j] = __builtin_amdgcn_mfma_f32_16x16x32_bf16(aa, bb, acc[j], 0, 0, 0);
    }
  }
#pragma unroll
  for (int j = 0; j < 4; j++) {
    if (j >= nst) break;
    int st = st0 + j;
#pragma unroll
    for (int r = 0; r < 4; r++)
      glog[(size_t)(bT + t0 + q * 4 + r) * SP + st * 16 + c] = acc[j][r] + bvs[j];
  }
}

// exponent-field renorm (trans-free), wave-reduced
#define RENORM4(A0, A1, A2, A3, KC) {                                           \
    long long ba0 = __double_as_longlong(A0), ba1 = __double_as_longlong(A1);   \
    long long ba2 = __double_as_longlong(A2), ba3 = __double_as_longlong(A3);   \
    int ee0 = (int)((ba0 >> 52) & 0x7FF), ee1 = (int)((ba1 >> 52) & 0x7FF);     \
    int ee2 = (int)((ba2 >> 52) & 0x7FF), ee3 = (int)((ba3 >> 52) & 0x7FF);     \
    int em = ee0 > ee1 ? ee0 : ee1;                                             \
    em = em > ee2 ? em : ee2;                                                   \
    em = em > ee3 ? em : ee3;                                                   \
    _Pragma("unroll")                                                           \
    for (int o = 1; o < 64; o <<= 1) { int q2 = __shfl_xor(em, o); em = em > q2 ? em : q2; } \
    if (em > 0 && em < 2046) {                                                  \
      double sc = __longlong_as_double((long long)(2046 - em) << 52);           \
      A0 *= sc; A1 *= sc; A2 *= sc; A3 *= sc;                                   \
      KC += em - 1023;                                                          \
    } }

// ---- DP kernel (standalone for exact attribution): 16 blocks x 2 waves,
//      fw/bw split, scaled linear FP64, LDS dbuf + counted vmcnt ----
__global__ __launch_bounds__(128) void k_dp(const float* __restrict__ glog,
                                            const int* __restrict__ labels,
                                            const int* __restrict__ hlens,
                                            const int* __restrict__ llens,
                                            float* __restrict__ rawtot) {
  // smem: buf0@0 buf1@13312 (fw) buf2@26624 buf3@39936 (bw)
  //       laf@53248 (208 f32)  lbf@54080 (208 f32)  -> 54912 total
  __shared__ __attribute__((aligned(16))) char smem[54912];
  int tid = threadIdx.x;
  int w = tid >> 6, l = tid & 63;
  int b = blockIdx.x;

  int col4 = ((4 * l < SP) ? 4 * l : SP - 4) * 4;
  const char* gvb = (const char*)glog + (size_t)b * T * RSTRIDE;
  int hl = hlens[b];
  int mfw = (hl - 1) >> 1;                   // fw steps; bw steps = hl-1-mfw
  const size_t gmax = (size_t)T * RSTRIDE - 16;

  int i0 = (2 * l < L) ? 2 * l : L - 1;
  int i1 = (2 * l + 1 < L) ? 2 * l + 1 : L - 1;
  int im = (l >= 1) ? 2 * l - 1 : 0; im = im < L ? im : L - 1;
  int lab0 = labels[b * L + i0];
  int lab1 = labels[b * L + i1];
  int labm = labels[b * L + im];
  bool sk1 = (l >= 1) && (lab0 != 0) && (lab0 != labm);
  bool sk3 = (lab1 != 0) && (lab1 != lab0);

  constexpr float LOG2E = 1.44269504f;
  float* laf = (float*)(smem + 53248);
  float* lbf = (float*)(smem + 54080);

  if (w == 0) {
    // ================= FORWARD: alpha_0 .. alpha_mfw =================
    f32x4 g0 = *(const f32x4*)(gvb + col4);       // t=0 row
    double z0 = (l == 0) ? 1.0 : 0.0;
    double z1 = (l == 0) ? (double)ex2((g0.y - g0.x) * LOG2E) : 0.0;
    double z2 = 0.0, z3 = 0.0;
    double Csum = (double)g0.x;
    int Kc = 0;

    auto stageF = [&](int cc, int dst) {
      size_t sb = (size_t)(1 + cc * CH) * RSTRIDE;
#pragma unroll
      for (int pg = 0; pg < 13; pg++) {
        size_t ob = sb + (size_t)pg * 1024 + (size_t)l * 16;
        if (ob > gmax) ob = gmax;
        __builtin_amdgcn_global_load_lds(
            (const __attribute__((address_space(1))) void*)(gvb + ob),
            (__attribute__((address_space(3))) void*)(smem + dst * CHB + pg * 1024),
            16, 0, 0);
      }
    };

#define FW_STEPZ(G) {                                                  \
    float e1f = ex2(((G).y - (G).x) * LOG2E);                          \
    float e3f = ex2(((G).w - (G).x) * LOG2E);                          \
    Csum += (double)(G).x;                                             \
    double p3 = dpp_shr1_zero_d(z3);                                   \
    double nz0 = z0 + p3;                                              \
    double nz1 = (z1 + z0 + (sk1 ? p3 : 0.0)) * (double)e1f;           \
    double nz2 = z2 + z1;                                              \
    double nz3 = (z3 + z2 + (sk3 ? z1 : 0.0)) * (double)e3f;           \
    z0 = nz0; z1 = nz1; z2 = nz2; z3 = nz3; }

    int nchF = (mfw + CH - 1) / CH;               // >= 13 (mfw >= 199)
    stageF(0, 0);
    stageF(1, 1);
    for (int c = 0; c < nchF; ++c) {
      int cur = c & 1;
      if (c + 2 < nchF) { asm volatile("s_waitcnt vmcnt(13)" ::: "memory"); }
      else             { asm volatile("s_waitcnt vmcnt(0)" ::: "memory"); }
      __builtin_amdgcn_sched_barrier(0);
      const char* bufc = smem + cur * CHB + col4;
      int steps = mfw - c * CH; if (steps > CH) steps = CH;
      if (steps == CH) {
        f32x4 G[8];
#pragma unroll
        for (int j = 0; j < 8; j++) G[j] = *(const f32x4*)(bufc + j * RSTRIDE);
#pragma unroll
        for (int j = 0; j < 8; j++) FW_STEPZ(G[j])
#pragma unroll
        for (int j = 0; j < 8; j++) G[j] = *(const f32x4*)(bufc + (8 + j) * RSTRIDE);
#pragma unroll
        for (int j = 0; j < 8; j++) FW_STEPZ(G[j])
        RENORM4(z0, z1, z2, z3, Kc)
      } else {
        for (int j = 0; j < steps; j++) {
          f32x4 G = *(const f32x4*)(bufc + j * RSTRIDE);
          FW_STEPZ(G)
        }
      }
      if (c + 2 < nchF) {
        asm volatile("s_waitcnt lgkmcnt(0)" ::: "memory");
        stageF(c + 2, cur);
      }
    }
#undef FW_STEPZ
    if (l < 52) {
      float base = (float)(Csum * 1.4426950408889634 + (double)Kc);
      laf[4 * l + 0] = base + lg2d(z0);
      laf[4 * l + 1] = base + lg2d(z1);
      laf[4 * l + 2] = base + lg2d(z2);
      laf[4 * l + 3] = base + lg2d(z3);
    }
  } else {
    // ================= BACKWARD: beta_{hl-1} .. beta_mfw =============
    int ll = llens[b];
    int sA = 2 * ll, sB = sA - 1;
    int s0i = 4 * l;
    double b0 = (s0i == sA || s0i == sB) ? 1.0 : 0.0;
    double b1 = (s0i + 1 == sA || s0i + 1 == sB) ? 1.0 : 0.0;
    double b2 = (s0i + 2 == sA || s0i + 2 == sB) ? 1.0 : 0.0;
    double b3 = (s0i + 3 == sA || s0i + 3 == sB) ? 1.0 : 0.0;
    double Csum = 0.0;
    int Kc = 0;
    int sk1i = sk1 ? 1 : 0;
    bool sk1n = __shfl_down(sk1i, 1) != 0;        // sk1 of lane l+1

    auto stageB = [&](int cc, int dst) {
      int rlo = hl - 1 - cc * CH - 15;            // >= 168 (hl>=400)
      size_t sb = (size_t)rlo * RSTRIDE;
#pragma unroll
      for (int pg = 0; pg < 13; pg++) {
        size_t ob = sb + (size_t)pg * 1024 + (size_t)l * 16;
        if (ob > gmax) ob = gmax;
        __builtin_amdgcn_global_load_lds(
            (const __attribute__((address_space(1))) void*)(gvb + ob),
            (__attribute__((address_space(3))) void*)(smem + dst * CHB + pg * 1024),
            16, 0, 0);
      }
    };

    // chain-shortened bw step: shl1(b1*e1) == shl1(b1)*shl1(e1) (bit-exact,
    // lane permutation distributes over the product); both factors off-chain.
#define BW_STEPZ(G) {                                                  \
    float e1f = ex2(((G).y - (G).x) * LOG2E);                          \
    float e3f = ex2(((G).w - (G).x) * LOG2E);                          \
    float e1s = dpp_shl1_zero_f(e1f);                                  \
    Csum += (double)(G).x;                                             \
    double b1s = dpp_shl1_zero_d(b1);                                  \
    double q4  = dpp_shl1_zero_d(b0);                                  \
    double f1 = b1 * (double)e1f;                                      \
    double f3 = b3 * (double)e3f;                                      \
    double q5 = b1s * (double)e1s;                                     \
    double nb0 = b0 + f1;                                              \
    double nb1 = f1 + b2 + (sk3 ? f3 : 0.0);                           \
    double nb2 = b2 + f3;                                              \
    double nb3 = f3 + q4 + (sk1n ? q5 : 0.0);                          \
    b0 = nb0; b1 = nb1; b2 = nb2; b3 = nb3; }

    int bsteps = (hl - 1) - mfw;
    int nchB = (bsteps + CH - 1) / CH;            // >= 13
    stageB(0, 2);
    stageB(1, 3);
    for (int c = 0; c < nchB; ++c) {
      int cur = c & 1;
      if (c + 2 < nchB) { asm volatile("s_waitcnt vmcnt(13)" ::: "memory"); }
      else             { asm volatile("s_waitcnt vmcnt(0)" ::: "memory"); }
      __builtin_amdgcn_sched_barrier(0);
      const char* bufc = smem + (2 + cur) * CHB + col4;
      int hi = hl - 1 - c * CH;                   // top row this chunk
      int steps = hi - mfw; if (steps > CH) steps = CH;
      if (steps == CH) {
        f32x4 G[8];
#pragma unroll
        for (int j = 0; j < 8; j++) G[j] = *(const f32x4*)(bufc + (15 - j) * RSTRIDE);
#pragma unroll
        for (int j = 0; j < 8; j++) BW_STEPZ(G[j])
#pragma unroll
        for (int j = 0; j < 8; j++) G[j] = *(const f32x4*)(bufc + (7 - j) * RSTRIDE);
#pragma unroll
        for (int j = 0; j < 8; j++) BW_STEPZ(G[j])
        RENORM4(b0, b1, b2, b3, Kc)
      } else {
        for (int j = 0; j < steps; j++) {
          f32x4 G = *(const f32x4*)(bufc + (15 - j) * RSTRIDE);
          BW_STEPZ(G)
        }
      }
      if (c + 2 < nchB) {
        asm volatile("s_waitcnt lgkmcnt(0)" ::: "memory");
        stageB(c + 2, 2 + cur);
      }
    }
#undef BW_STEPZ
    if (l < 52) {
      float base = (float)(Csum * 1.4426950408889634 + (double)Kc);
      lbf[4 * l + 0] = base + lg2d(b0);
      lbf[4 * l + 1] = base + lg2d(b1);
      lbf[4 * l + 2] = base + lg2d(b2);
      lbf[4 * l + 3] = base + lg2d(b3);
    }
  }

  __syncthreads();
  if (w == 0) {
    // junction: log2 P = LSE2_s (la[s] + lb[s]) over s < S
    float v[4];
#pragma unroll
    for (int r = 0; r < 4; r++) {
      int s = 4 * l + r;
      v[r] = (l < 52 && s < S) ? (laf[s] + lbf[s]) : -1.0e30f;
    }
    float mx = fmaxf(fmaxf(v[0], v[1]), fmaxf(v[2], v[3]));
#pragma unroll
    for (int o = 1; o < 64; o <<= 1) mx = fmaxf(mx, __shfl_xor(mx, o));
    float ssum = ex2(v[0] - mx) + ex2(v[1] - mx) + ex2(v[2] - mx) + ex2(v[3] - mx);
#pragma unroll
    for (int o = 1; o < 64; o <<= 1) ssum += __shfl_xor(ssum, o);
    if (l == 0)
      rawtot[b] = 0.6931471805599453f * (mx + lg2(ssum));
  }
}

// ---- GEMM + softmax partials (pure; DP moved to k_dp) ----
__global__ __launch_bounds__(256) void k_fused(const unsigned short* __restrict__ A,
                                               const unsigned short* __restrict__ Wt,
                                               const float* __restrict__ bias,
                                               float* __restrict__ partM,
                                               float* __restrict__ partS) {
  __shared__ unsigned short As[128 * 64];
  __shared__ unsigned short Bs[128 * 64];
  __shared__ float redM[2][128];
  __shared__ float redS[2][128];

  int gblk = blockIdx.x;
  int cb = gblk % NCB, rb = gblk / NCB;
  int tid = threadIdx.x;
  int lane = tid & 63, w = tid >> 6;
  int q = lane >> 4, c = lane & 15;
  int mh = w & 1, nh = w >> 1;
  int row0 = rb * 128, n0 = cb * 128;
  int lr = lane >> 3, lc = lane & 7;
  int oc = (lc ^ lr) * 8;

  f32x4 acc[4][4];
#pragma unroll
  for (int mt = 0; mt < 4; mt++)
#pragma unroll
    for (int nt = 0; nt < 4; nt++) acc[mt][nt] = (f32x4){0.f, 0.f, 0.f, 0.f};

  for (int kk = 0; kk < D; kk += 64) {
#pragma unroll
    for (int j = 0; j < 4; j++) {
      int i = w * 4 + j;
      const unsigned short* ga = A + (size_t)(row0 + i * 8 + lr) * D + kk + oc;
      __builtin_amdgcn_global_load_lds(
          (const __attribute__((address_space(1))) void*)ga,
          (__attribute__((address_space(3))) void*)(As + i * 512), 16, 0, 0);
      const unsigned short* gb = Wt + (size_t)(n0 + i * 8 + lr) * D + kk + oc;
      __builtin_amdgcn_global_load_lds(
          (const __attribute__((address_space(1))) void*)gb,
          (__attribute__((address_space(3))) void*)(Bs + i * 512), 16, 0, 0);
    }
    __syncthreads();
#pragma unroll
    for (int kq = 0; kq < 2; kq++) {
      int o = ((kq * 4 + q) ^ (c & 7)) * 8;
      bf16x8 af[4], bfr[4];
#pragma unroll
      for (int mt = 0; mt < 4; mt++)
        af[mt] = *(const bf16x8*)(As + (mh * 64 + mt * 16 + c) * 64 + o);
#pragma unroll
      for (int nt = 0; nt < 4; nt++)
        bfr[nt] = *(const bf16x8*)(Bs + (nh * 64 + nt * 16 + c) * 64 + o);
#pragma unroll
      for (int mt = 0; mt < 4; mt++)
#pragma unroll
        for (int nt = 0; nt < 4; nt++)
          acc[mt][nt] = __builtin_amdgcn_mfma_f32_16x16x32_bf16(af[mt], bfr[nt], acc[mt][nt], 0, 0, 0);
    }
    __syncthreads();
  }

  int vcb[4]; float bv[4];
#pragma unroll
  for (int nt = 0; nt < 4; nt++) {
    vcb[nt] = n0 + nh * 64 + nt * 16 + c;
    bv[nt] = (vcb[nt] < V) ? bias[vcb[nt]] : 0.f;
  }
#pragma unroll
  for (int mt = 0; mt < 4; mt++) {
#pragma unroll
    for (int r = 0; r < 4; r++) {
      float x[4]; float m = NEG_INF;
#pragma unroll
      for (int nt = 0; nt < 4; nt++) {
        x[nt] = (vcb[nt] < V) ? (acc[mt][nt][r] + bv[nt]) : NEG_INF;
        m = fmaxf(m, x[nt]);
      }
#pragma unroll
      for (int o = 1; o < 16; o <<= 1) m = fmaxf(m, __shfl_xor(m, o));
      float s = 0.f;
#pragma unroll
      for (int nt = 0; nt < 4; nt++) s += __expf(x[nt] - m);
#pragma unroll
      for (int o = 1; o < 16; o <<= 1) s += __shfl_xor(s, o);
      if (c == 0) {
        int rloc = mh * 64 + mt * 16 + q * 4 + r;
        redM[nh][rloc] = m;
        redS[nh][rloc] = s;
      }
    }
  }
  __syncthreads();
  if (tid < 128) {
    float m0 = redM[0][tid], m1 = redM[1][tid];
    float mm = fmaxf(m0, m1);
    float ss = redS[0][tid] * __expf(m0 - mm) + redS[1][tid] * __expf(m1 - mm);
    partM[(size_t)cb * ROWS + row0 + tid] = mm;
    partS[(size_t)cb * ROWS + row0 + tid] = ss;
  }
}

// ---- combine 40 partials -> lse[row] ----
__global__ __launch_bounds__(256) void k_lse(const float* __restrict__ pM,
                                             const float* __restrict__ pS,
                                             float* __restrict__ lse) {
  int row = blockIdx.x * 256 + threadIdx.x;
  float m = pM[row], s = pS[row];
  for (int cb = 1; cb < NCB; cb++) {
    float M2 = pM[(size_t)cb * ROWS + row], S2 = pS[(size_t)cb * ROWS + row];
    float mn = fmaxf(m, M2);
    s = s * __expf(m - mn) + S2 * __expf(M2 - mn);
    m = mn;
  }
  lse[row] = m + __logf(s);
}

// ---- final: tot[b] = rawtot[b] - sum_{t<hl} lse[b,t]; out = mean(-tot) ----
__global__ __launch_bounds__(1024) void k_final(const float* __restrict__ lse,
                                                const float* __restrict__ rawtot,
                                                const int* __restrict__ hlens,
                                                float* __restrict__ out) {
  __shared__ float acc[Bb];
  int w = threadIdx.x >> 6, l = threadIdx.x & 63;  // 16 waves, one per b
  int hl = hlens[w];
  float s = 0.f;
  for (int t = l; t < hl; t += 64) s += lse[w * T + t];
#pragma unroll
  for (int o = 1; o < 64; o <<= 1) s += __shfl_xor(s, o);
  if (l == 0) acc[w] = rawtot[w] - s;
  __syncthreads();
  if (threadIdx.x == 0) {
    float m = 0.f;
    for (int i = 0; i < Bb; i++) m += acc[i];
    out[0] = -m / (float)Bb;
  }
}

extern "C" void kernel_launch(void* const* d_in, const int* in_sizes, int n_in,
                              void* d_out, int out_size, void* d_ws, size_t ws_size,
                              hipStream_t stream) {
  const float* hs    = (const float*)d_in[0];
  const float* W     = (const float*)d_in[1];
  const float* bias  = (const float*)d_in[2];
  const int* hlens   = (const int*)d_in[3];
  const int* labels  = (const int*)d_in[4];
  const int* llens   = (const int*)d_in[5];
  float* out = (float*)d_out;

  char* ws = (char*)d_ws;
  unsigned short* A    = (unsigned short*)(ws);              // 12800*512*2 = 13,107,200
  unsigned short* Wt   = (unsigned short*)(ws + 13107200);   // 5120*512*2  =  5,242,880
  float*          partM= (float*)(ws + 18350080);            // 40*12800*4  =  2,048,000
  float*          partS= (float*)(ws + 20398080);            // 40*12800*4  =  2,048,000
  float*          lse  = (float*)(ws + 22446080);            // 12800*4     =     51,200
  float*          glog = (float*)(ws + 22497280);            // 12800*208*4 = 10,649,600
  float*          rawtot=(float*)(ws + 33146880);            // 16*4

  k_prep<<<CONVB + (VP / 64) * (D / 64), 256, 0, stream>>>(hs, W, A, Wt);
  k_gather<<<NGB, 256, 0, stream>>>(A, Wt, bias, labels, glog);
  k_dp<<<Bb, 128, 0, stream>>>(glog, labels, hlens, llens, rawtot);
  k_fused<<<NCB * NRB, 256, 0, stream>>>(A, Wt, bias, partM, partS);
  k_lse<<<ROWS / 256, 256, 0, stream>>>(partM, partS, lse);
  k_final<<<1, 1024, 0, stream>>>(lse, rawtot, hlens, out);

  (void)in_sizes; (void)n_in; (void)out_size; (void)ws_size;
}

// Round 15
// 241.575 us; speedup vs baseline: 1.2556x; 1.2556x over previous
//
#include <hip/hip_runtime.h>

#define NEG_INF -1e30f

typedef __attribute__((ext_vector_type(8))) __bf16 bf16x8;
typedef __attribute__((ext_vector_type(4))) float f32x4;

constexpr int Bb = 16, T = 800, D = 512, V = 5000, L = 100;
constexpr int ROWS = Bb * T;        // 12800
constexpr int S = 2 * L + 1;        // 201
constexpr int SP = 208;             // padded S (13*16)
constexpr int VP = 5120;            // V padded to 128
constexpr int NCB = VP / 128;       // 40 col-blocks (GEMM)
constexpr int NRB = ROWS / 128;     // 100 row-blocks
constexpr int NGB = Bb * 50;        // 800 gather blocks
constexpr int CONVB = ROWS * D / 1024;  // 6400 conv blocks
constexpr int RSTRIDE = SP * 4;     // 832 bytes per glog row
constexpr int CH = 16;              // DP chunk (t-steps per LDS buffer)
constexpr int CHB = CH * RSTRIDE;   // 13312 bytes per chunk buffer

// float -> bf16 bits, round-to-nearest-even
static __device__ __forceinline__ unsigned short f2bf(float x) {
  union { float f; unsigned u; } v; v.f = x;
  unsigned r = (v.u + 0x7FFFu + ((v.u >> 16) & 1u)) >> 16;
  return (unsigned short)r;
}

// wave_shr:1 (0x138): lane i gets lane i-1; old=0 for lane 0
static __device__ __forceinline__ double dpp_shr1_zero_d(double x) {
  long long b = __double_as_longlong(x);
  int lo = (int)(b & 0xFFFFFFFFLL);
  int hi = (int)(b >> 32);
  int nlo = __builtin_amdgcn_update_dpp(0, lo, 0x138, 0xF, 0xF, false);
  int nhi = __builtin_amdgcn_update_dpp(0, hi, 0x138, 0xF, 0xF, false);
  return __longlong_as_double(((long long)(unsigned)nlo) | ((long long)nhi << 32));
}
// wave_shl:1 (0x130): lane i gets lane i+1; old=0 for lane 63
static __device__ __forceinline__ double dpp_shl1_zero_d(double x) {
  long long b = __double_as_longlong(x);
  int lo = (int)(b & 0xFFFFFFFFLL);
  int hi = (int)(b >> 32);
  int nlo = __builtin_amdgcn_update_dpp(0, lo, 0x130, 0xF, 0xF, false);
  int nhi = __builtin_amdgcn_update_dpp(0, hi, 0x130, 0xF, 0xF, false);
  return __longlong_as_double(((long long)(unsigned)nlo) | ((long long)nhi << 32));
}
static __device__ __forceinline__ float dpp_shl1_zero_f(float x) {
  return __int_as_float(__builtin_amdgcn_update_dpp(
      0, __float_as_int(x), 0x130, 0xF, 0xF, false));
}

// native base-2 transcendentals
static __device__ __forceinline__ float ex2(float x) { return __builtin_amdgcn_exp2f(x); }
static __device__ __forceinline__ float lg2(float x) { return __builtin_amdgcn_logf(x); }

// log2 of a positive double via exponent field + f32 mantissa log
static __device__ __forceinline__ float lg2d(double z) {
  long long b = __double_as_longlong(z);
  int e = (int)((b >> 52) & 0x7FF);
  if (e == 0) return -1.0e30f;            // zero/subnormal -> semiring zero
  unsigned mant = (unsigned)((b >> 29) & 0x7FFFFFu);
  float mf = __int_as_float(0x3F800000u | mant);
  return (float)(e - 1023) + lg2(mf);
}

// ---- PREP: conv_hs (blocks 0..6399) + transW (6400..7039) ----
__global__ __launch_bounds__(256) void k_prep(const float* __restrict__ hs,
                                              const float* __restrict__ W,
                                              unsigned short* __restrict__ A,
                                              unsigned short* __restrict__ Wt) {
  __shared__ float tile[64][65];
  int blk = blockIdx.x;
  if (blk < CONVB) {
    int i = blk * 256 + threadIdx.x;
    float4 f = ((const float4*)hs)[i];
    ushort4 o;
    o.x = f2bf(f.x); o.y = f2bf(f.y); o.z = f2bf(f.z); o.w = f2bf(f.w);
    ((ushort4*)A)[i] = o;
    return;
  }
  int g = blk - CONVB;                 // 0..639
  int v0 = (g % (VP / 64)) * 64, k0 = (g / (VP / 64)) * 64;
  int tl = threadIdx.x & 63, th = threadIdx.x >> 6;
#pragma unroll
  for (int i = 0; i < 16; i++) {
    int k = k0 + th + i * 4;
    int v = v0 + tl;
    tile[th + i * 4][tl] = (v < V) ? W[(size_t)k * V + v] : 0.f;
  }
  __syncthreads();
#pragma unroll
  for (int i = 0; i < 16; i++) {
    int v = v0 + th + i * 4;
    int k = k0 + tl;
    Wt[(size_t)v * D + k] = f2bf(tile[tl][th + i * 4]);
  }
}

// ---- gathered RAW logits: one block per (b, 16-t chunk) ----
__global__ __launch_bounds__(256) void k_gather(const unsigned short* __restrict__ A,
                                                const unsigned short* __restrict__ Wt,
                                                const float* __restrict__ bias,
                                                const int* __restrict__ labels,
                                                float* __restrict__ glog) {
  int tid = threadIdx.x;
  int lane = tid & 63, w = tid >> 6;
  int q = lane >> 4, c = lane & 15;
  int b = blockIdx.x & 15, chk = blockIdx.x >> 4;
  int t0 = chk * 16;
  int bT = b * T, bL = b * L;
  int st0 = (w == 0) ? 0 : 4 + (w - 1) * 3;   // tiles: 4,3,3,3
  int nst = (w == 0) ? 4 : 3;

  int evs[4]; float bvs[4];
#pragma unroll
  for (int j = 0; j < 4; j++) {
    int st = st0 + (j < nst ? j : nst - 1);
    int s = st * 16 + c;
    evs[j] = (s < S && (s & 1)) ? labels[bL + (s >> 1)] : 0;
    bvs[j] = bias[evs[j]];
  }
  const unsigned short* Arow = A + (size_t)(bT + t0 + c) * D;
  f32x4 acc[4];
#pragma unroll
  for (int j = 0; j < 4; j++) acc[j] = (f32x4){0.f, 0.f, 0.f, 0.f};
  for (int kk = 0; kk < D; kk += 32) {
    bf16x8 aa = *(const bf16x8*)(Arow + kk + q * 8);
#pragma unroll
    for (int j = 0; j < 4; j++) {
      bf16x8 bb = *(const bf16x8*)(Wt + (size_t)evs[j] * D + kk + q * 8);
      acc[j] = __builtin_amdgcn_mfma_f32_16x16x32_bf16(aa, bb, acc[j], 0, 0, 0);
    }
  }
#pragma unroll
  for (int j = 0; j < 4; j++) {
    if (j >= nst) break;
    int st = st0 + j;
#pragma unroll
    for (int r = 0; r < 4; r++)
      glog[(size_t)(bT + t0 + q * 4 + r) * SP + st * 16 + c] = acc[j][r] + bvs[j];
  }
}

// exponent-field renorm (trans-free), wave-reduced
#define RENORM4(A0, A1, A2, A3, KC) {                                           \
    long long ba0 = __double_as_longlong(A0), ba1 = __double_as_longlong(A1);   \
    long long ba2 = __double_as_longlong(A2), ba3 = __double_as_longlong(A3);   \
    int ee0 = (int)((ba0 >> 52) & 0x7FF), ee1 = (int)((ba1 >> 52) & 0x7FF);     \
    int ee2 = (int)((ba2 >> 52) & 0x7FF), ee3 = (int)((ba3 >> 52) & 0x7FF);     \
    int em = ee0 > ee1 ? ee0 : ee1;                                             \
    em = em > ee2 ? em : ee2;                                                   \
    em = em > ee3 ? em : ee3;                                                   \
    _Pragma("unroll")                                                           \
    for (int o = 1; o < 64; o <<= 1) { int q2 = __shfl_xor(em, o); em = em > q2 ? em : q2; } \
    if (em > 0 && em < 2046) {                                                  \
      double sc = __longlong_as_double((long long)(2046 - em) << 52);           \
      A0 *= sc; A1 *= sc; A2 *= sc; A3 *= sc;                                   \
      KC += em - 1023;                                                          \
    } }

// ---- FUSED: blocks 0..15 = CTC DP (fw/bw split, FP64 scaled linear, LDS
//      dbuf + counted vmcnt); blocks 16.. = 2-PHASE PIPELINED GEMM:
//      issue next K-tile's global_load_lds BEFORE computing current tile,
//      one barrier per K-step -> load latency hides under MFMA ----
__global__ __launch_bounds__(256) void k_fused(const unsigned short* __restrict__ A,
                                               const unsigned short* __restrict__ Wt,
                                               const float* __restrict__ bias,
                                               const float* __restrict__ glog,
                                               const int* __restrict__ labels,
                                               const int* __restrict__ hlens,
                                               const int* __restrict__ llens,
                                               float* __restrict__ partM,
                                               float* __restrict__ partS,
                                               float* __restrict__ rawtot) {
  // GEMM: As dbuf @0/16384, Bs dbuf @32768/49152; redM@0 redS@1024 (epilogue
  //       only -- As region is dead after the K-loop's final barrier).
  // DP:   buf0@0 buf1@13312 (fw) buf2@26624 buf3@39936 (bw), laf@53248, lbf@54080
  __shared__ __attribute__((aligned(16))) char smem[65536];

  int blk = blockIdx.x;
  if (blk < Bb) {
    // ==================== DP path (2 waves; waves 2-3 exit) ===============
    int tid = threadIdx.x;
    int w = tid >> 6, l = tid & 63;
    if (w >= 2) { __syncthreads(); return; }

    int b = blk;
    int col4 = ((4 * l < SP) ? 4 * l : SP - 4) * 4;
    const char* gvb = (const char*)glog + (size_t)b * T * RSTRIDE;
    int hl = hlens[b];
    int mfw = (hl - 1) >> 1;                   // fw steps; bw = hl-1-mfw
    const size_t gmax = (size_t)T * RSTRIDE - 16;

    int i0 = (2 * l < L) ? 2 * l : L - 1;
    int i1 = (2 * l + 1 < L) ? 2 * l + 1 : L - 1;
    int im = (l >= 1) ? 2 * l - 1 : 0; im = im < L ? im : L - 1;
    int lab0 = labels[b * L + i0];
    int lab1 = labels[b * L + i1];
    int labm = labels[b * L + im];
    bool sk1 = (l >= 1) && (lab0 != 0) && (lab0 != labm);
    bool sk3 = (lab1 != 0) && (lab1 != lab0);

    constexpr float LOG2E = 1.44269504f;
    float* laf = (float*)(smem + 53248);
    float* lbf = (float*)(smem + 54080);

    if (w == 0) {
      // FORWARD: alpha_0 .. alpha_mfw
      f32x4 g0 = *(const f32x4*)(gvb + col4);       // t=0 row
      double z0 = (l == 0) ? 1.0 : 0.0;
      double z1 = (l == 0) ? (double)ex2((g0.y - g0.x) * LOG2E) : 0.0;
      double z2 = 0.0, z3 = 0.0;
      double Csum = (double)g0.x;
      int Kc = 0;

      auto stageF = [&](int cc, int dst) {
        size_t sb = (size_t)(1 + cc * CH) * RSTRIDE;
#pragma unroll
        for (int pg = 0; pg < 13; pg++) {
          size_t ob = sb + (size_t)pg * 1024 + (size_t)l * 16;
          if (ob > gmax) ob = gmax;
          __builtin_amdgcn_global_load_lds(
              (const __attribute__((address_space(1))) void*)(gvb + ob),
              (__attribute__((address_space(3))) void*)(smem + dst * CHB + pg * 1024),
              16, 0, 0);
        }
      };

#define FW_STEPZ(G) {                                                  \
    float e1f = ex2(((G).y - (G).x) * LOG2E);                          \
    float e3f = ex2(((G).w - (G).x) * LOG2E);                          \
    Csum += (double)(G).x;                                             \
    double p3 = dpp_shr1_zero_d(z3);                                   \
    double nz0 = z0 + p3;                                              \
    double nz1 = (z1 + z0 + (sk1 ? p3 : 0.0)) * (double)e1f;           \
    double nz2 = z2 + z1;                                              \
    double nz3 = (z3 + z2 + (sk3 ? z1 : 0.0)) * (double)e3f;           \
    z0 = nz0; z1 = nz1; z2 = nz2; z3 = nz3; }

      int nchF = (mfw + CH - 1) / CH;               // >= 13
      stageF(0, 0);
      stageF(1, 1);
      for (int c = 0; c < nchF; ++c) {
        int cur = c & 1;
        if (c + 2 < nchF) { asm volatile("s_waitcnt vmcnt(13)" ::: "memory"); }
        else             { asm volatile("s_waitcnt vmcnt(0)" ::: "memory"); }
        __builtin_amdgcn_sched_barrier(0);
        const char* bufc = smem + cur * CHB + col4;
        int steps = mfw - c * CH; if (steps > CH) steps = CH;
        if (steps == CH) {
          f32x4 G[8];
#pragma unroll
          for (int j = 0; j < 8; j++) G[j] = *(const f32x4*)(bufc + j * RSTRIDE);
#pragma unroll
          for (int j = 0; j < 8; j++) FW_STEPZ(G[j])
#pragma unroll
          for (int j = 0; j < 8; j++) G[j] = *(const f32x4*)(bufc + (8 + j) * RSTRIDE);
#pragma unroll
          for (int j = 0; j < 8; j++) FW_STEPZ(G[j])
          RENORM4(z0, z1, z2, z3, Kc)
        } else {
          for (int j = 0; j < steps; j++) {
            f32x4 G = *(const f32x4*)(bufc + j * RSTRIDE);
            FW_STEPZ(G)
          }
        }
        if (c + 2 < nchF) {
          asm volatile("s_waitcnt lgkmcnt(0)" ::: "memory");
          stageF(c + 2, cur);
        }
      }
#undef FW_STEPZ
      if (l < 52) {
        float base = (float)(Csum * 1.4426950408889634 + (double)Kc);
        laf[4 * l + 0] = base + lg2d(z0);
        laf[4 * l + 1] = base + lg2d(z1);
        laf[4 * l + 2] = base + lg2d(z2);
        laf[4 * l + 3] = base + lg2d(z3);
      }
    } else {
      // BACKWARD: beta_{hl-1} .. beta_mfw
      int ll = llens[b];
      int sA = 2 * ll, sB = sA - 1;
      int s0i = 4 * l;
      double b0 = (s0i == sA || s0i == sB) ? 1.0 : 0.0;
      double b1 = (s0i + 1 == sA || s0i + 1 == sB) ? 1.0 : 0.0;
      double b2 = (s0i + 2 == sA || s0i + 2 == sB) ? 1.0 : 0.0;
      double b3 = (s0i + 3 == sA || s0i + 3 == sB) ? 1.0 : 0.0;
      double Csum = 0.0;
      int Kc = 0;
      int sk1i = sk1 ? 1 : 0;
      bool sk1n = __shfl_down(sk1i, 1) != 0;        // sk1 of lane l+1

      auto stageB = [&](int cc, int dst) {
        int rlo = hl - 1 - cc * CH - 15;            // >= 168 (hl>=400)
        size_t sb = (size_t)rlo * RSTRIDE;
#pragma unroll
        for (int pg = 0; pg < 13; pg++) {
          size_t ob = sb + (size_t)pg * 1024 + (size_t)l * 16;
          if (ob > gmax) ob = gmax;
          __builtin_amdgcn_global_load_lds(
              (const __attribute__((address_space(1))) void*)(gvb + ob),
              (__attribute__((address_space(3))) void*)(smem + dst * CHB + pg * 1024),
              16, 0, 0);
        }
      };

      // chain-shortened: shl1(b1*e1) == shl1(b1)*shl1(e1), both off-chain
#define BW_STEPZ(G) {                                                  \
    float e1f = ex2(((G).y - (G).x) * LOG2E);                          \
    float e3f = ex2(((G).w - (G).x) * LOG2E);                          \
    float e1s = dpp_shl1_zero_f(e1f);                                  \
    Csum += (double)(G).x;                                             \
    double b1s = dpp_shl1_zero_d(b1);                                  \
    double q4  = dpp_shl1_zero_d(b0);                                  \
    double f1 = b1 * (double)e1f;                                      \
    double f3 = b3 * (double)e3f;                                      \
    double q5 = b1s * (double)e1s;                                     \
    double nb0 = b0 + f1;                                              \
    double nb1 = f1 + b2 + (sk3 ? f3 : 0.0);                           \
    double nb2 = b2 + f3;                                              \
    double nb3 = f3 + q4 + (sk1n ? q5 : 0.0);                          \
    b0 = nb0; b1 = nb1; b2 = nb2; b3 = nb3; }

      int bsteps = (hl - 1) - mfw;
      int nchB = (bsteps + CH - 1) / CH;            // >= 13
      stageB(0, 2);
      stageB(1, 3);
      for (int c = 0; c < nchB; ++c) {
        int cur = c & 1;
        if (c + 2 < nchB) { asm volatile("s_waitcnt vmcnt(13)" ::: "memory"); }
        else             { asm volatile("s_waitcnt vmcnt(0)" ::: "memory"); }
        __builtin_amdgcn_sched_barrier(0);
        const char* bufc = smem + (2 + cur) * CHB + col4;
        int hi = hl - 1 - c * CH;                   // top row this chunk
        int steps = hi - mfw; if (steps > CH) steps = CH;
        if (steps == CH) {
          f32x4 G[8];
#pragma unroll
          for (int j = 0; j < 8; j++) G[j] = *(const f32x4*)(bufc + (15 - j) * RSTRIDE);
#pragma unroll
          for (int j = 0; j < 8; j++) BW_STEPZ(G[j])
#pragma unroll
          for (int j = 0; j < 8; j++) G[j] = *(const f32x4*)(bufc + (7 - j) * RSTRIDE);
#pragma unroll
          for (int j = 0; j < 8; j++) BW_STEPZ(G[j])
          RENORM4(b0, b1, b2, b3, Kc)
        } else {
          for (int j = 0; j < steps; j++) {
            f32x4 G = *(const f32x4*)(bufc + (15 - j) * RSTRIDE);
            BW_STEPZ(G)
          }
        }
        if (c + 2 < nchB) {
          asm volatile("s_waitcnt lgkmcnt(0)" ::: "memory");
          stageB(c + 2, 2 + cur);
        }
      }
#undef BW_STEPZ
      if (l < 52) {
        float base = (float)(Csum * 1.4426950408889634 + (double)Kc);
        lbf[4 * l + 0] = base + lg2d(b0);
        lbf[4 * l + 1] = base + lg2d(b1);
        lbf[4 * l + 2] = base + lg2d(b2);
        lbf[4 * l + 3] = base + lg2d(b3);
      }
    }

    __syncthreads();
    if (w == 0) {
      // junction: log2 P = LSE2_s (la[s] + lb[s]) over s < S
      float v[4];
#pragma unroll
      for (int r = 0; r < 4; r++) {
        int s = 4 * l + r;
        v[r] = (l < 52 && s < S) ? (laf[s] + lbf[s]) : -1.0e30f;
      }
      float mx = fmaxf(fmaxf(v[0], v[1]), fmaxf(v[2], v[3]));
#pragma unroll
      for (int o = 1; o < 64; o <<= 1) mx = fmaxf(mx, __shfl_xor(mx, o));
      float ssum = ex2(v[0] - mx) + ex2(v[1] - mx) + ex2(v[2] - mx) + ex2(v[3] - mx);
#pragma unroll
      for (int o = 1; o < 64; o <<= 1) ssum += __shfl_xor(ssum, o);
      if (l == 0)
        rawtot[b] = 0.6931471805599453f * (mx + lg2(ssum));
    }
    return;
  }

  // ============== GEMM path: 2-phase pipelined, XOR-swizzled LDS ==========
  int gblk = blk - Bb;
  int cb = gblk % NCB, rb = gblk / NCB;
  int tid = threadIdx.x;
  int lane = tid & 63, w = tid >> 6;
  int q = lane >> 4, c = lane & 15;
  int mh = w & 1, nh = w >> 1;
  int row0 = rb * 128, n0 = cb * 128;
  int lr = lane >> 3, lc = lane & 7;
  int oc = (lc ^ lr) * 8;

  auto stageG = [&](int bufsel, int kk) {
#pragma unroll
    for (int j = 0; j < 4; j++) {
      int i = w * 4 + j;
      const unsigned short* ga = A + (size_t)(row0 + i * 8 + lr) * D + kk + oc;
      __builtin_amdgcn_global_load_lds(
          (const __attribute__((address_space(1))) void*)ga,
          (__attribute__((address_space(3))) void*)(smem + bufsel * 16384 + i * 1024),
          16, 0, 0);
      const unsigned short* gb = Wt + (size_t)(n0 + i * 8 + lr) * D + kk + oc;
      __builtin_amdgcn_global_load_lds(
          (const __attribute__((address_space(1))) void*)gb,
          (__attribute__((address_space(3))) void*)(smem + 32768 + bufsel * 16384 + i * 1024),
          16, 0, 0);
    }
  };

  f32x4 acc[4][4];
#pragma unroll
  for (int mt = 0; mt < 4; mt++)
#pragma unroll
    for (int nt = 0; nt < 4; nt++) acc[mt][nt] = (f32x4){0.f, 0.f, 0.f, 0.f};

  stageG(0, 0);
  __syncthreads();            // prologue drain (once)
  int cur = 0;
  for (int kt = 0; kt < 8; kt++) {
    if (kt + 1 < 8) stageG(cur ^ 1, (kt + 1) * 64);   // issue BEFORE compute
    const unsigned short* Ab = (const unsigned short*)(smem + cur * 16384);
    const unsigned short* Bb2 = (const unsigned short*)(smem + 32768 + cur * 16384);
#pragma unroll
    for (int kq = 0; kq < 2; kq++) {
      int o = ((kq * 4 + q) ^ (c & 7)) * 8;
      bf16x8 af[4], bfr[4];
#pragma unroll
      for (int mt = 0; mt < 4; mt++)
        af[mt] = *(const bf16x8*)(Ab + (mh * 64 + mt * 16 + c) * 64 + o);
#pragma unroll
      for (int nt = 0; nt < 4; nt++)
        bfr[nt] = *(const bf16x8*)(Bb2 + (nh * 64 + nt * 16 + c) * 64 + o);
#pragma unroll
      for (int mt = 0; mt < 4; mt++)
#pragma unroll
        for (int nt = 0; nt < 4; nt++)
          acc[mt][nt] = __builtin_amdgcn_mfma_f32_16x16x32_bf16(af[mt], bfr[nt], acc[mt][nt], 0, 0, 0);
    }
    __syncthreads();          // single barrier/K-step: drain covered by compute
    cur ^= 1;
  }

  // epilogue: redM/redS alias the (now dead) As region
  float (*redM)[128] = (float (*)[128])(smem + 0);
  float (*redS)[128] = (float (*)[128])(smem + 1024);

  int vcb[4]; float bv[4];
#pragma unroll
  for (int nt = 0; nt < 4; nt++) {
    vcb[nt] = n0 + nh * 64 + nt * 16 + c;
    bv[nt] = (vcb[nt] < V) ? bias[vcb[nt]] : 0.f;
  }
#pragma unroll
  for (int mt = 0; mt < 4; mt++) {
#pragma unroll
    for (int r = 0; r < 4; r++) {
      float x[4]; float m = NEG_INF;
#pragma unroll
      for (int nt = 0; nt < 4; nt++) {
        x[nt] = (vcb[nt] < V) ? (acc[mt][nt][r] + bv[nt]) : NEG_INF;
        m = fmaxf(m, x[nt]);
      }
#pragma unroll
      for (int o = 1; o < 16; o <<= 1) m = fmaxf(m, __shfl_xor(m, o));
      float s = 0.f;
#pragma unroll
      for (int nt = 0; nt < 4; nt++) s += __expf(x[nt] - m);
#pragma unroll
      for (int o = 1; o < 16; o <<= 1) s += __shfl_xor(s, o);
      if (c == 0) {
        int rloc = mh * 64 + mt * 16 + q * 4 + r;
        redM[nh][rloc] = m;
        redS[nh][rloc] = s;
      }
    }
  }
  __syncthreads();
  if (tid < 128) {
    float m0 = redM[0][tid], m1 = redM[1][tid];
    float mm = fmaxf(m0, m1);
    float ss = redS[0][tid] * __expf(m0 - mm) + redS[1][tid] * __expf(m1 - mm);
    partM[(size_t)cb * ROWS + row0 + tid] = mm;
    partS[(size_t)cb * ROWS + row0 + tid] = ss;
  }
}

// ---- combine 40 partials -> lse[row] ----
__global__ __launch_bounds__(256) void k_lse(const float* __restrict__ pM,
                                             const float* __restrict__ pS,
                                             float* __restrict__ lse) {
  int row = blockIdx.x * 256 + threadIdx.x;
  float m = pM[row], s = pS[row];
  for (int cb = 1; cb < NCB; cb++) {
    float M2 = pM[(size_t)cb * ROWS + row], S2 = pS[(size_t)cb * ROWS + row];
    float mn = fmaxf(m, M2);
    s = s * __expf(m - mn) + S2 * __expf(M2 - mn);
    m = mn;
  }
  lse[row] = m + __logf(s);
}

// ---- final: tot[b] = rawtot[b] - sum_{t<hl} lse[b,t]; out = mean(-tot) ----
__global__ __launch_bounds__(1024) void k_final(const float* __restrict__ lse,
                                                const float* __restrict__ rawtot,
                                                const int* __restrict__ hlens,
                                                float* __restrict__ out) {
  __shared__ float acc[Bb];
  int w = threadIdx.x >> 6, l = threadIdx.x & 63;  // 16 waves, one per b
  int hl = hlens[w];
  float s = 0.f;
  for (int t = l; t < hl; t += 64) s += lse[w * T + t];
#pragma unroll
  for (int o = 1; o < 64; o <<= 1) s += __shfl_xor(s, o);
  if (l == 0) acc[w] = rawtot[w] - s;
  __syncthreads();
  if (threadIdx.x == 0) {
    float m = 0.f;
    for (int i = 0; i < Bb; i++) m += acc[i];
    out[0] = -m / (float)Bb;
  }
}

extern "C" void kernel_launch(void* const* d_in, const int* in_sizes, int n_in,
                              void* d_out, int out_size, void* d_ws, size_t ws_size,
                              hipStream_t stream) {
  const float* hs    = (const float*)d_in[0];
  const float* W     = (const float*)d_in[1];
  const float* bias  = (const float*)d_in[2];
  const int* hlens   = (const int*)d_in[3];
  const int* labels  = (const int*)d_in[4];
  const int* llens   = (const int*)d_in[5];
  float* out = (float*)d_out;

  char* ws = (char*)d_ws;
  unsigned short* A    = (unsigned short*)(ws);              // 12800*512*2 = 13,107,200
  unsigned short* Wt   = (unsigned short*)(ws + 13107200);   // 5120*512*2  =  5,242,880
  float*          partM= (float*)(ws + 18350080);            // 40*12800*4  =  2,048,000
  float*          partS= (float*)(ws + 20398080);            // 40*12800*4  =  2,048,000
  float*          lse  = (float*)(ws + 22446080);            // 12800*4     =     51,200
  float*          glog = (float*)(ws + 22497280);            // 12800*208*4 = 10,649,600
  float*          rawtot=(float*)(ws + 33146880);            // 16*4

  k_prep<<<CONVB + (VP / 64) * (D / 64), 256, 0, stream>>>(hs, W, A, Wt);
  k_gather<<<NGB, 256, 0, stream>>>(A, Wt, bias, labels, glog);
  k_fused<<<Bb + NCB * NRB, 256, 0, stream>>>(A, Wt, bias, glog, labels, hlens, llens,
                                              partM, partS, rawtot);
  k_lse<<<ROWS / 256, 256, 0, stream>>>(partM, partS, lse);
  k_final<<<1, 1024, 0, stream>>>(lse, rawtot, hlens, out);

  (void)in_sizes; (void)n_in; (void)out_size; (void)ws_size;
}